// Round 1
// baseline (427.454 us; speedup 1.0000x reference)
//
#include <hip/hip_runtime.h>

// FeatNeighbourCorr: feats [B=8, C=128, H=256, W=256] fp32 ->
// out [B, 8, H, W] fp32. out[b,k,h,w] = sum_c nf[b,c,h,w]*nf[b,c,rh,rw]
// where nf = feats / ||feats||_C and (rh,rw) = reflect(h-dx, w-dy).
//
// Single pass: accumulate 9 squared-sums (3x3 window) + 8 dot products per
// pixel over C, then combine with rsqrt. feats read ~once from HBM (halo
// re-reads hit L1/L2). Block = 64x8 pixel tile (waves along w: coalesced
// 256B lines per row per channel).

#define BB 8
#define CC 128
#define HH 256
#define WW 256

__global__ __launch_bounds__(512) void featcorr_kernel(
    const float* __restrict__ feats, float* __restrict__ out) {
  const int w = blockIdx.x * 64 + threadIdx.x;
  const int h = blockIdx.y * 8 + threadIdx.y;
  const int b = blockIdx.z;

  // reflect-pad (d=1): -1 -> 1, H -> H-2
  const int hm = (h == 0) ? 1 : h - 1;
  const int hp = (h == HH - 1) ? HH - 2 : h + 1;
  const int wm = (w == 0) ? 1 : w - 1;
  const int wp = (w == WW - 1) ? WW - 2 : w + 1;

  const size_t HW = (size_t)HH * WW;
  const float* base = feats + (size_t)b * CC * HW;

  const int rm = hm * WW, r0 = h * WW, rp = hp * WW;
  const int o00 = rm + wm, o01 = rm + w, o02 = rm + wp;
  const int o10 = r0 + wm, o11 = r0 + w, o12 = r0 + wp;
  const int o20 = rp + wm, o21 = rp + w, o22 = rp + wp;

  float s00 = 0.f, s01 = 0.f, s02 = 0.f;
  float s10 = 0.f, s11 = 0.f, s12 = 0.f;
  float s20 = 0.f, s21 = 0.f, s22 = 0.f;
  float d0 = 0.f, d1 = 0.f, d2 = 0.f, d3 = 0.f;
  float d4 = 0.f, d5 = 0.f, d6 = 0.f, d7 = 0.f;

#pragma unroll 4
  for (int c = 0; c < CC; ++c) {
    const float* p = base + (size_t)c * HW;
    const float v00 = p[o00], v01 = p[o01], v02 = p[o02];
    const float v10 = p[o10], v11 = p[o11], v12 = p[o12];
    const float v20 = p[o20], v21 = p[o21], v22 = p[o22];
    s00 += v00 * v00; s01 += v01 * v01; s02 += v02 * v02;
    s10 += v10 * v10; s11 += v11 * v11; s12 += v12 * v12;
    s20 += v20 * v20; s21 += v21 * v21; s22 += v22 * v22;
    d0 += v11 * v01;  // k0: (dx,dy)=( 1, 0) -> (h-1, w  )
    d1 += v11 * v00;  // k1: ( 1, 1) -> (h-1, w-1)
    d2 += v11 * v10;  // k2: ( 0, 1) -> (h,   w-1)
    d3 += v11 * v20;  // k3: (-1, 1) -> (h+1, w-1)
    d4 += v11 * v21;  // k4: (-1, 0) -> (h+1, w  )
    d5 += v11 * v22;  // k5: (-1,-1) -> (h+1, w+1)
    d6 += v11 * v12;  // k6: ( 0,-1) -> (h,   w+1)
    d7 += v11 * v02;  // k7: ( 1,-1) -> (h-1, w+1)
  }

  const float i00 = rsqrtf(s00), i01 = rsqrtf(s01), i02 = rsqrtf(s02);
  const float i10 = rsqrtf(s10), i11 = rsqrtf(s11), i12 = rsqrtf(s12);
  const float i20 = rsqrtf(s20), i21 = rsqrtf(s21), i22 = rsqrtf(s22);

  // out layout: ((b*8 + k)*H + h)*W + w
  float* o = out + (size_t)b * 8 * HW + (size_t)h * WW + w;
  o[0 * HW] = d0 * i11 * i01;
  o[1 * HW] = d1 * i11 * i00;
  o[2 * HW] = d2 * i11 * i10;
  o[3 * HW] = d3 * i11 * i20;
  o[4 * HW] = d4 * i11 * i21;
  o[5 * HW] = d5 * i11 * i22;
  o[6 * HW] = d6 * i11 * i12;
  o[7 * HW] = d7 * i11 * i02;
}

extern "C" void kernel_launch(void* const* d_in, const int* in_sizes, int n_in,
                              void* d_out, int out_size, void* d_ws, size_t ws_size,
                              hipStream_t stream) {
  const float* feats = (const float*)d_in[0];
  float* out = (float*)d_out;
  dim3 block(64, 8, 1);
  dim3 grid(WW / 64, HH / 8, BB);
  featcorr_kernel<<<grid, block, 0, stream>>>(feats, out);
}

// Round 2
// 384.949 us; speedup vs baseline: 1.1104x; 1.1104x over previous
//
#include <hip/hip_runtime.h>

// FeatNeighbourCorr: feats [B=8, C=128, H=256, W=256] fp32 ->
// out [B, 8, H, W] fp32.
// out[b,k,h,w] = dot_k * rsqrt(ssq_center) * rsqrt(ssq_neighbor_k)
//
// Layout: one block = one (b, h) row. 4 waves x 64 lanes; each lane owns 4
// consecutive columns (float4), so ONE wave spans the full 256-px row:
// all +-1 column neighbors come from __shfl (reflect at w=0/255 stays inside
// the lane's own float4 -> zero halo loads). Each wave handles 32 channels
// (3 x global_load_dwordx4 per channel); 44 accumulators/lane reduced across
// the 4 waves via LDS, wave 0 does the epilogue.

#define BB 8
#define CC 128
#define HH 256
#define WW 256
#define CSPLIT 4
#define CPW (CC / CSPLIT)

#define SQT(j) acc[(j)]
#define SQM(j) acc[4 + (j)]
#define SQB(j) acc[8 + (j)]
#define DD(k, j) acc[12 + (k)*4 + (j)]

__global__ __launch_bounds__(256) void featcorr_kernel(
    const float* __restrict__ feats, float* __restrict__ out) {
  const int lane = threadIdx.x;  // 0..63
  const int wy = threadIdx.y;    // 0..3
  const int h = blockIdx.x;
  const int b = blockIdx.y;

  const int hm = (h == 0) ? 1 : h - 1;
  const int hp = (h == HH - 1) ? HH - 2 : h + 1;

  const size_t HW = (size_t)HH * WW;
  const int col0 = lane * 4;

  const float* pT = feats + ((size_t)b * CC + wy * CPW) * HW + (size_t)hm * WW + col0;
  const float* pM = feats + ((size_t)b * CC + wy * CPW) * HW + (size_t)h * WW + col0;
  const float* pB = feats + ((size_t)b * CC + wy * CPW) * HW + (size_t)hp * WW + col0;

  float acc[44];
#pragma unroll
  for (int a = 0; a < 44; ++a) acc[a] = 0.f;

#pragma unroll 2
  for (int c = 0; c < CPW; ++c) {
    const float4 t4 = *(const float4*)pT;
    const float4 m4 = *(const float4*)pM;
    const float4 b4 = *(const float4*)pB;
    pT += HW; pM += HW; pB += HW;

    // Column arrays over cols [col0-1 .. col0+4]; px j sits at index j+1.
    float T[6], M[6], B[6];
    T[1] = t4.x; T[2] = t4.y; T[3] = t4.z; T[4] = t4.w;
    M[1] = m4.x; M[2] = m4.y; M[3] = m4.z; M[4] = m4.w;
    B[1] = b4.x; B[2] = b4.y; B[3] = b4.z; B[4] = b4.w;

    const float tL = __shfl_up(t4.w, 1), mL = __shfl_up(m4.w, 1), bL = __shfl_up(b4.w, 1);
    const float tR = __shfl_down(t4.x, 1), mR = __shfl_down(m4.x, 1), bR = __shfl_down(b4.x, 1);
    // reflect: col -1 -> col 1 (own .y); col 256 -> col 254 (own .z)
    T[0] = (lane == 0) ? t4.y : tL;
    M[0] = (lane == 0) ? m4.y : mL;
    B[0] = (lane == 0) ? b4.y : bL;
    T[5] = (lane == 63) ? t4.z : tR;
    M[5] = (lane == 63) ? m4.z : mR;
    B[5] = (lane == 63) ? b4.z : bR;

#pragma unroll
    for (int j = 0; j < 4; ++j) {
      SQT(j) += T[j + 1] * T[j + 1];
      SQM(j) += M[j + 1] * M[j + 1];
      SQB(j) += B[j + 1] * B[j + 1];
      const float mc = M[j + 1];
      DD(0, j) += mc * T[j + 1];  // k0: (h-1, w  )
      DD(1, j) += mc * T[j];      // k1: (h-1, w-1)
      DD(2, j) += mc * M[j];      // k2: (h,   w-1)
      DD(3, j) += mc * B[j];      // k3: (h+1, w-1)
      DD(4, j) += mc * B[j + 1];  // k4: (h+1, w  )
      DD(5, j) += mc * B[j + 2];  // k5: (h+1, w+1)
      DD(6, j) += mc * M[j + 2];  // k6: (h,   w+1)
      DD(7, j) += mc * T[j + 2];  // k7: (h-1, w+1)
    }
  }

  // ---- cross-wave reduction: waves {1,3} -> {0,2}, then 2 -> 0 ----
  __shared__ float lds[2][44][64];
  if (wy == 1) {
#pragma unroll
    for (int a = 0; a < 44; ++a) lds[0][a][lane] = acc[a];
  }
  if (wy == 3) {
#pragma unroll
    for (int a = 0; a < 44; ++a) lds[1][a][lane] = acc[a];
  }
  __syncthreads();
  if (wy == 0) {
#pragma unroll
    for (int a = 0; a < 44; ++a) acc[a] += lds[0][a][lane];
  }
  if (wy == 2) {
#pragma unroll
    for (int a = 0; a < 44; ++a) acc[a] += lds[1][a][lane];
  }
  __syncthreads();
  if (wy == 2) {
#pragma unroll
    for (int a = 0; a < 44; ++a) lds[0][a][lane] = acc[a];
  }
  __syncthreads();

  if (wy == 0) {
#pragma unroll
    for (int a = 0; a < 44; ++a) acc[a] += lds[0][a][lane];

    float iT[4], iM[4], iB[4];
#pragma unroll
    for (int j = 0; j < 4; ++j) {
      iT[j] = rsqrtf(SQT(j));
      iM[j] = rsqrtf(SQM(j));
      iB[j] = rsqrtf(SQB(j));
    }
    // neighbor inverse norms over cols [col0-1 .. col0+4]
    float IT[6], IM[6], IB[6];
    IT[1] = iT[0]; IT[2] = iT[1]; IT[3] = iT[2]; IT[4] = iT[3];
    IM[1] = iM[0]; IM[2] = iM[1]; IM[3] = iM[2]; IM[4] = iM[3];
    IB[1] = iB[0]; IB[2] = iB[1]; IB[3] = iB[2]; IB[4] = iB[3];
    const float itL = __shfl_up(iT[3], 1), imL = __shfl_up(iM[3], 1), ibL = __shfl_up(iB[3], 1);
    const float itR = __shfl_down(iT[0], 1), imR = __shfl_down(iM[0], 1), ibR = __shfl_down(iB[0], 1);
    IT[0] = (lane == 0) ? iT[1] : itL;
    IM[0] = (lane == 0) ? iM[1] : imL;
    IB[0] = (lane == 0) ? iB[1] : ibL;
    IT[5] = (lane == 63) ? iT[2] : itR;
    IM[5] = (lane == 63) ? iM[2] : imR;
    IB[5] = (lane == 63) ? iB[2] : ibR;

    float* obase = out + ((size_t)b * 8) * HW + (size_t)h * WW + col0;
#pragma unroll
    for (int k = 0; k < 8; ++k) {
      float4 o;
      float v[4];
#pragma unroll
      for (int j = 0; j < 4; ++j) {
        const float ic = iM[j];
        float in;
        switch (k) {
          case 0: in = IT[j + 1]; break;
          case 1: in = IT[j];     break;
          case 2: in = IM[j];     break;
          case 3: in = IB[j];     break;
          case 4: in = IB[j + 1]; break;
          case 5: in = IB[j + 2]; break;
          case 6: in = IM[j + 2]; break;
          default: in = IT[j + 2]; break;
        }
        v[j] = DD(k, j) * ic * in;
      }
      o.x = v[0]; o.y = v[1]; o.z = v[2]; o.w = v[3];
      *(float4*)(obase + (size_t)k * HW) = o;
    }
  }
}

extern "C" void kernel_launch(void* const* d_in, const int* in_sizes, int n_in,
                              void* d_out, int out_size, void* d_ws, size_t ws_size,
                              hipStream_t stream) {
  const float* feats = (const float*)d_in[0];
  float* out = (float*)d_out;
  dim3 block(64, CSPLIT, 1);
  dim3 grid(HH, BB, 1);
  featcorr_kernel<<<grid, block, 0, stream>>>(feats, out);
}

// Round 3
// 365.810 us; speedup vs baseline: 1.1685x; 1.0523x over previous
//
#include <hip/hip_runtime.h>

// FeatNeighbourCorr: feats [B=8, C=128, H=256, W=256] fp32 -> out [B,8,H,W] fp32.
// out[b,k,h,w] = dot_k(h,w) * rsqrt(ssq(h,w)) * rsqrt(ssq(neighbor_k))
//
// One block = one (b,h) row, 2 waves x 64 lanes, 64 channels/wave.
// Lane owns 4 consecutive cols (float4). Per channel: 3 global_load_dwordx4
// (rows h-1,h,h+1) + 3 shfl_down (right neighbor's .x) + 44 FMAs.
// Left-boundary dot terms (k1/k2/k3 of px0) are computed by the LEFT lane
// (eK accumulators stored in the DD(1..3,0) slots) and delivered with one
// shfl_up after the loop; reflect edges resolve by symmetry:
//   lane 0:  DD(1,0)=DD(7,0), DD(2,0)=DD(6,0), DD(3,0)=DD(5,0)
//   lane 63: DD(5,3)=DD(3,3), DD(6,3)=DD(2,3), DD(7,3)=DD(1,3)
// Depth-2 software pipeline keeps 6 loads in flight per wave.
// 128-thr blocks + 11KB LDS -> all 2048 blocks resident in one round.

#define BB 8
#define CC 128
#define HH 256
#define WW 256
#define CSPLIT 2
#define CPW (CC / CSPLIT)  // 64

#define DD(k, j) acc[12 + (k)*4 + (j)]

__global__ __launch_bounds__(128) void featcorr_kernel(
    const float* __restrict__ feats, float* __restrict__ out) {
  const int lane = threadIdx.x;  // 0..63
  const int wy = threadIdx.y;    // 0..1
  // XCD-strip swizzle: blocks round-robin XCDs; give XCD k a contiguous
  // 32-row strip so the 3-row windows of adjacent h hit the same L2.
  const int h = (blockIdx.x % 8) * (HH / 8) + (blockIdx.x / 8);
  const int b = blockIdx.y;

  const int hm = (h == 0) ? 1 : h - 1;
  const int hp = (h == HH - 1) ? HH - 2 : h + 1;

  const size_t HW = (size_t)HH * WW;
  const int col0 = lane * 4;

  const float* pT = feats + ((size_t)b * CC + wy * CPW) * HW + (size_t)hm * WW + col0;
  const float* pM = feats + ((size_t)b * CC + wy * CPW) * HW + (size_t)h * WW + col0;
  const float* pB = feats + ((size_t)b * CC + wy * CPW) * HW + (size_t)hp * WW + col0;

  float acc[44];
#pragma unroll
  for (int a = 0; a < 44; ++a) acc[a] = 0.f;

  auto compute = [&](const float4 t, const float4 m, const float4 bt) {
    const float rT = __shfl_down(t.x, 1);
    const float rM = __shfl_down(m.x, 1);
    const float rB = __shfl_down(bt.x, 1);
    // squared sums (rows hm / h / hp)
    acc[0] += t.x * t.x;  acc[1] += t.y * t.y;  acc[2] += t.z * t.z;  acc[3] += t.w * t.w;
    acc[4] += m.x * m.x;  acc[5] += m.y * m.y;  acc[6] += m.z * m.z;  acc[7] += m.w * m.w;
    acc[8] += bt.x * bt.x; acc[9] += bt.y * bt.y; acc[10] += bt.z * bt.z; acc[11] += bt.w * bt.w;
    // k0 (h-1, w)
    DD(0, 0) += m.x * t.x; DD(0, 1) += m.y * t.y; DD(0, 2) += m.z * t.z; DD(0, 3) += m.w * t.w;
    // k4 (h+1, w)
    DD(4, 0) += m.x * bt.x; DD(4, 1) += m.y * bt.y; DD(4, 2) += m.z * bt.z; DD(4, 3) += m.w * bt.w;
    // k1 (h-1, w-1): j=1..3 local; slot (1,0) = eK1 for right lane's px0
    DD(1, 1) += m.y * t.x; DD(1, 2) += m.z * t.y; DD(1, 3) += m.w * t.z;
    DD(1, 0) += rM * t.w;
    // k2 (h, w-1)
    DD(2, 1) += m.y * m.x; DD(2, 2) += m.z * m.y; DD(2, 3) += m.w * m.z;
    DD(2, 0) += rM * m.w;
    // k3 (h+1, w-1)
    DD(3, 1) += m.y * bt.x; DD(3, 2) += m.z * bt.y; DD(3, 3) += m.w * bt.z;
    DD(3, 0) += rM * bt.w;
    // k5 (h+1, w+1)
    DD(5, 0) += m.x * bt.y; DD(5, 1) += m.y * bt.z; DD(5, 2) += m.z * bt.w; DD(5, 3) += m.w * rB;
    // k6 (h, w+1)
    DD(6, 0) += m.x * m.y; DD(6, 1) += m.y * m.z; DD(6, 2) += m.z * m.w; DD(6, 3) += m.w * rM;
    // k7 (h-1, w+1)
    DD(7, 0) += m.x * t.y; DD(7, 1) += m.y * t.z; DD(7, 2) += m.z * t.w; DD(7, 3) += m.w * rT;
  };

  // ---- depth-2 pipelined channel loop ----
  float4 tA = *(const float4*)pT, mA = *(const float4*)pM, bA = *(const float4*)pB;
  pT += HW; pM += HW; pB += HW;
  float4 tB = *(const float4*)pT, mB = *(const float4*)pM, bB = *(const float4*)pB;
  pT += HW; pM += HW; pB += HW;

#pragma unroll 2
  for (int c = 0; c < CPW - 2; ++c) {
    const float4 tC = *(const float4*)pT;
    const float4 mC = *(const float4*)pM;
    const float4 bC = *(const float4*)pB;
    pT += HW; pM += HW; pB += HW;
    compute(tA, mA, bA);
    tA = tB; mA = mB; bA = bB;
    tB = tC; mB = mC; bB = bC;
  }
  compute(tA, mA, bA);
  compute(tB, mB, bB);

  // ---- cross-wave reduction (single LDS buffer, 11 KB) ----
  __shared__ float lds[44][64];
  if (wy == 1) {
#pragma unroll
    for (int a = 0; a < 44; ++a) lds[a][lane] = acc[a];
  }
  __syncthreads();

  if (wy == 0) {
#pragma unroll
    for (int a = 0; a < 44; ++a) acc[a] += lds[a][lane];

    // deliver left-lane boundary dots; reflect edges via symmetry
    const float g1 = __shfl_up(DD(1, 0), 1);
    const float g2 = __shfl_up(DD(2, 0), 1);
    const float g3 = __shfl_up(DD(3, 0), 1);
    DD(1, 0) = (lane == 0) ? DD(7, 0) : g1;
    DD(2, 0) = (lane == 0) ? DD(6, 0) : g2;
    DD(3, 0) = (lane == 0) ? DD(5, 0) : g3;
    if (lane == 63) {
      DD(5, 3) = DD(3, 3);
      DD(6, 3) = DD(2, 3);
      DD(7, 3) = DD(1, 3);
    }

    float it[4], im[4], ib[4];
#pragma unroll
    for (int j = 0; j < 4; ++j) {
      it[j] = rsqrtf(acc[j]);
      im[j] = rsqrtf(acc[4 + j]);
      ib[j] = rsqrtf(acc[8 + j]);
    }
    // neighbor inverse norms over cols [col0-1 .. col0+4]
    float IT[6], IM[6], IB[6];
    IT[1] = it[0]; IT[2] = it[1]; IT[3] = it[2]; IT[4] = it[3];
    IM[1] = im[0]; IM[2] = im[1]; IM[3] = im[2]; IM[4] = im[3];
    IB[1] = ib[0]; IB[2] = ib[1]; IB[3] = ib[2]; IB[4] = ib[3];
    const float tl = __shfl_up(it[3], 1), ml = __shfl_up(im[3], 1), bl = __shfl_up(ib[3], 1);
    const float tr = __shfl_down(it[0], 1), mr = __shfl_down(im[0], 1), br = __shfl_down(ib[0], 1);
    IT[0] = (lane == 0) ? it[1] : tl;
    IM[0] = (lane == 0) ? im[1] : ml;
    IB[0] = (lane == 0) ? ib[1] : bl;
    IT[5] = (lane == 63) ? it[2] : tr;
    IM[5] = (lane == 63) ? im[2] : mr;
    IB[5] = (lane == 63) ? ib[2] : br;

    float* obase = out + ((size_t)b * 8) * HW + (size_t)h * WW + col0;
#pragma unroll
    for (int k = 0; k < 8; ++k) {
      float v[4];
#pragma unroll
      for (int j = 0; j < 4; ++j) {
        float in;
        switch (k) {
          case 0: in = it[j];     break;  // (h-1, w)
          case 1: in = IT[j];     break;  // (h-1, w-1)
          case 2: in = IM[j];     break;  // (h,   w-1)
          case 3: in = IB[j];     break;  // (h+1, w-1)
          case 4: in = ib[j];     break;  // (h+1, w)
          case 5: in = IB[j + 2]; break;  // (h+1, w+1)
          case 6: in = IM[j + 2]; break;  // (h,   w+1)
          default: in = IT[j + 2]; break; // (h-1, w+1)
        }
        v[j] = DD(k, j) * im[j] * in;
      }
      float4 o;
      o.x = v[0]; o.y = v[1]; o.z = v[2]; o.w = v[3];
      *(float4*)(obase + (size_t)k * HW) = o;
    }
  }
}

extern "C" void kernel_launch(void* const* d_in, const int* in_sizes, int n_in,
                              void* d_out, int out_size, void* d_ws, size_t ws_size,
                              hipStream_t stream) {
  const float* feats = (const float*)d_in[0];
  float* out = (float*)d_out;
  dim3 block(64, CSPLIT, 1);
  dim3 grid(HH, BB, 1);
  featcorr_kernel<<<grid, block, 0, stream>>>(feats, out);
}

// Round 4
// 364.593 us; speedup vs baseline: 1.1724x; 1.0033x over previous
//
#include <hip/hip_runtime.h>

// FeatNeighbourCorr: feats [B=8, C=128, H=256, W=256] fp32 -> out [B,8,H,W] fp32.
// out[b,k,h,w] = dot_k(h,w) * rsqrt(ssq(h,w)) * rsqrt(ssq(neighbor_k))
//
// One block = one (b,h) row, 2 waves x 64 lanes, 64 channels/wave.
// Lane owns 4 consecutive cols (float4). Per channel: 3 global_load_dwordx4
// (rows h-1,h,h+1) + 3 shfl_down (right neighbor's .x) + ~40 FMAs.
// Cross-lane boundary dot terms are accumulated by the LEFT lane and
// delivered with one shfl_up after the loop; reflect edges resolve by
// symmetry (see exchange section).
// DEPTH-4 register pipeline: 12 dwordx4 loads (192 B/lane) in flight,
// 3-channel lookahead -> ~1200 cyc latency tolerance at 4 waves/SIMD,
// enough to cover ~900 cyc HBM latency -> HBM-BW-bound.

#define BB 8
#define CC 128
#define HH 256
#define WW 256
#define CSPLIT 2
#define CPW (CC / CSPLIT)  // 64

#define DD(k, j) acc[12 + (k)*4 + (j)]

__global__ __launch_bounds__(128) void featcorr_kernel(
    const float* __restrict__ feats, float* __restrict__ out) {
  const int lane = threadIdx.x;  // 0..63
  const int wy = threadIdx.y;    // 0..1
  // XCD-strip swizzle: blocks round-robin XCDs; give each XCD a contiguous
  // 32-row strip so the 3-row windows of adjacent h hit the same L2.
  const int h = (blockIdx.x % 8) * (HH / 8) + (blockIdx.x / 8);
  const int b = blockIdx.y;

  const int hm = (h == 0) ? 1 : h - 1;
  const int hp = (h == HH - 1) ? HH - 2 : h + 1;

  const size_t HW = (size_t)HH * WW;
  const int col0 = lane * 4;

  const float* pT = feats + ((size_t)b * CC + wy * CPW) * HW + (size_t)hm * WW + col0;
  const float* pM = feats + ((size_t)b * CC + wy * CPW) * HW + (size_t)h * WW + col0;
  const float* pB = feats + ((size_t)b * CC + wy * CPW) * HW + (size_t)hp * WW + col0;

  float acc[44];
#pragma unroll
  for (int a = 0; a < 44; ++a) acc[a] = 0.f;

  auto compute = [&](const float4 t, const float4 m, const float4 bt) {
    const float rT = __shfl_down(t.x, 1);
    const float rM = __shfl_down(m.x, 1);
    const float rB = __shfl_down(bt.x, 1);
    // squared sums (rows hm / h / hp)
    acc[0] += t.x * t.x;  acc[1] += t.y * t.y;  acc[2] += t.z * t.z;  acc[3] += t.w * t.w;
    acc[4] += m.x * m.x;  acc[5] += m.y * m.y;  acc[6] += m.z * m.z;  acc[7] += m.w * m.w;
    acc[8] += bt.x * bt.x; acc[9] += bt.y * bt.y; acc[10] += bt.z * bt.z; acc[11] += bt.w * bt.w;
    // k0 (h-1, w)
    DD(0, 0) += m.x * t.x; DD(0, 1) += m.y * t.y; DD(0, 2) += m.z * t.z; DD(0, 3) += m.w * t.w;
    // k4 (h+1, w)
    DD(4, 0) += m.x * bt.x; DD(4, 1) += m.y * bt.y; DD(4, 2) += m.z * bt.z; DD(4, 3) += m.w * bt.w;
    // k1 (h-1, w-1): j=1..3 local; slot (1,0) = boundary term for right lane
    DD(1, 1) += m.y * t.x; DD(1, 2) += m.z * t.y; DD(1, 3) += m.w * t.z;
    DD(1, 0) += rM * t.w;
    // k2 (h, w-1): boundary term rM*m.w == k6 boundary m.w*rM -> merged into DD(6,3)
    DD(2, 1) += m.y * m.x; DD(2, 2) += m.z * m.y; DD(2, 3) += m.w * m.z;
    // k3 (h+1, w-1)
    DD(3, 1) += m.y * bt.x; DD(3, 2) += m.z * bt.y; DD(3, 3) += m.w * bt.z;
    DD(3, 0) += rM * bt.w;
    // k5 (h+1, w+1)
    DD(5, 0) += m.x * bt.y; DD(5, 1) += m.y * bt.z; DD(5, 2) += m.z * bt.w; DD(5, 3) += m.w * rB;
    // k6 (h, w+1); DD(6,3) doubles as the k2 boundary term for lane+1
    DD(6, 0) += m.x * m.y; DD(6, 1) += m.y * m.z; DD(6, 2) += m.z * m.w; DD(6, 3) += m.w * rM;
    // k7 (h-1, w+1)
    DD(7, 0) += m.x * t.y; DD(7, 1) += m.y * t.z; DD(7, 2) += m.z * t.w; DD(7, 3) += m.w * rT;
  };

#define LOADSTEP(T, M, Bv)        \
  T = *(const float4*)pT;         \
  M = *(const float4*)pM;         \
  Bv = *(const float4*)pB;        \
  pT += HW; pM += HW; pB += HW;

  // ---- depth-4 pipelined channel loop (64 channels/wave) ----
  float4 tA, mA, bA, tB, mB, bB, tC, mC, bC, tD, mD, bD;
  LOADSTEP(tA, mA, bA)   // ch 0
  LOADSTEP(tB, mB, bB)   // ch 1
  LOADSTEP(tC, mC, bC)   // ch 2

  for (int i = 0; i < CPW / 4 - 1; ++i) {  // computes ch 4i..4i+3
    LOADSTEP(tD, mD, bD) compute(tA, mA, bA);
    LOADSTEP(tA, mA, bA) compute(tB, mB, bB);
    LOADSTEP(tB, mB, bB) compute(tC, mC, bC);
    LOADSTEP(tC, mC, bC) compute(tD, mD, bD);
  }
  LOADSTEP(tD, mD, bD) compute(tA, mA, bA);  // load ch63, compute ch60
  compute(tB, mB, bB);
  compute(tC, mC, bC);
  compute(tD, mD, bD);

  // ---- cross-wave reduction (single LDS buffer, 11 KB) ----
  __shared__ float lds[44][64];
  if (wy == 1) {
#pragma unroll
    for (int a = 0; a < 44; ++a) lds[a][lane] = acc[a];
  }
  __syncthreads();

  if (wy == 0) {
#pragma unroll
    for (int a = 0; a < 44; ++a) acc[a] += lds[a][lane];

    // deliver left-lane boundary dots; reflect edges via symmetry
    const float g1 = __shfl_up(DD(1, 0), 1);
    const float g2 = __shfl_up(DD(6, 3), 1);  // merged k2 boundary
    const float g3 = __shfl_up(DD(3, 0), 1);
    DD(1, 0) = (lane == 0) ? DD(7, 0) : g1;
    DD(2, 0) = (lane == 0) ? DD(6, 0) : g2;
    DD(3, 0) = (lane == 0) ? DD(5, 0) : g3;
    if (lane == 63) {
      DD(5, 3) = DD(3, 3);
      DD(6, 3) = DD(2, 3);
      DD(7, 3) = DD(1, 3);
    }

    float it[4], im[4], ib[4];
#pragma unroll
    for (int j = 0; j < 4; ++j) {
      it[j] = rsqrtf(acc[j]);
      im[j] = rsqrtf(acc[4 + j]);
      ib[j] = rsqrtf(acc[8 + j]);
    }
    // neighbor inverse norms over cols [col0-1 .. col0+4]
    float IT[6], IM[6], IB[6];
    IT[1] = it[0]; IT[2] = it[1]; IT[3] = it[2]; IT[4] = it[3];
    IM[1] = im[0]; IM[2] = im[1]; IM[3] = im[2]; IM[4] = im[3];
    IB[1] = ib[0]; IB[2] = ib[1]; IB[3] = ib[2]; IB[4] = ib[3];
    const float tl = __shfl_up(it[3], 1), ml = __shfl_up(im[3], 1), bl = __shfl_up(ib[3], 1);
    const float tr = __shfl_down(it[0], 1), mr = __shfl_down(im[0], 1), br = __shfl_down(ib[0], 1);
    IT[0] = (lane == 0) ? it[1] : tl;
    IM[0] = (lane == 0) ? im[1] : ml;
    IB[0] = (lane == 0) ? ib[1] : bl;
    IT[5] = (lane == 63) ? it[2] : tr;
    IM[5] = (lane == 63) ? im[2] : mr;
    IB[5] = (lane == 63) ? ib[2] : br;

    float* obase = out + ((size_t)b * 8) * HW + (size_t)h * WW + col0;
#pragma unroll
    for (int k = 0; k < 8; ++k) {
      float v[4];
#pragma unroll
      for (int j = 0; j < 4; ++j) {
        float in;
        switch (k) {
          case 0: in = it[j];     break;  // (h-1, w)
          case 1: in = IT[j];     break;  // (h-1, w-1)
          case 2: in = IM[j];     break;  // (h,   w-1)
          case 3: in = IB[j];     break;  // (h+1, w-1)
          case 4: in = ib[j];     break;  // (h+1, w)
          case 5: in = IB[j + 2]; break;  // (h+1, w+1)
          case 6: in = IM[j + 2]; break;  // (h,   w+1)
          default: in = IT[j + 2]; break; // (h-1, w+1)
        }
        v[j] = DD(k, j) * im[j] * in;
      }
      float4 o;
      o.x = v[0]; o.y = v[1]; o.z = v[2]; o.w = v[3];
      *(float4*)(obase + (size_t)k * HW) = o;
    }
  }
}

extern "C" void kernel_launch(void* const* d_in, const int* in_sizes, int n_in,
                              void* d_out, int out_size, void* d_ws, size_t ws_size,
                              hipStream_t stream) {
  const float* feats = (const float*)d_in[0];
  float* out = (float*)d_out;
  dim3 block(64, CSPLIT, 1);
  dim3 grid(HH, BB, 1);
  featcorr_kernel<<<grid, block, 0, stream>>>(feats, out);
}